// Round 3
// baseline (363.340 us; speedup 1.0000x reference)
//
#include <hip/hip_runtime.h>

#define VOCAB 128000
#define EMBED 256
#define BATCH 64
#define TBLOCK 2048
#define ROWS (BATCH * TBLOCK)   // 131072 rows

#define RPW 8                   // rows per wave
#define WPB 4                   // waves per 256-thread block
#define ROWS_PER_BLOCK (RPW * WPB)  // 32

typedef float v4f __attribute__((ext_vector_type(4)));  // clang-native float4

// ---------------------------------------------------------------------------
// K1: cache-warming prefetch. Pure random-read phase: gather every needed
// embedding row once, discard the values (asm sink keeps loads live).
// Leaves the ~84MB unique-row working set resident in the 256MB Infinity
// Cache so K2's gathers become L3 hits instead of HBM random reads.
// ---------------------------------------------------------------------------
__global__ __launch_bounds__(256) void warm_kernel(
    const int* __restrict__ idx,
    const float* __restrict__ emb)
{
    const int lane = threadIdx.x & 63;
    const int wid  = blockIdx.x * WPB + (threadIdx.x >> 6);
    const long long rowbase = (long long)wid * RPW;

    const int4* ip = reinterpret_cast<const int4*>(idx + rowbase);
    const int4 i0 = ip[0];
    const int4 i1 = ip[1];
    int rows[RPW];
    rows[0] = i0.x; rows[1] = i0.y; rows[2] = i0.z; rows[3] = i0.w;
    rows[4] = i1.x; rows[5] = i1.y; rows[6] = i1.z; rows[7] = i1.w;

    float acc = 0.0f;
    #pragma unroll
    for (int r = 0; r < RPW; ++r) {
        const v4f* rowp =
            reinterpret_cast<const v4f*>(emb + (long long)rows[r] * EMBED);
        const v4f v = rowp[lane];
        acc += (v.x + v.y) + (v.z + v.w);
    }
    // keep the loads live without any store (guide rule #17)
    asm volatile("" :: "v"(acc));
}

// ---------------------------------------------------------------------------
// K2: the verified compute kernel (round-2). Gathers now hit L3 (warmed by
// K1); nontemporal stores stream the 268MB of output without evicting the
// warmed table lines.
// ---------------------------------------------------------------------------
__global__ __launch_bounds__(256) void embed_expnorm_kernel(
    const int* __restrict__ idx,
    const float* __restrict__ emb,
    float* __restrict__ logits,
    float* __restrict__ probs)
{
    const int lane = threadIdx.x & 63;
    const int wid  = blockIdx.x * WPB + (threadIdx.x >> 6);
    const long long rowbase = (long long)wid * RPW;

    const int4* ip = reinterpret_cast<const int4*>(idx + rowbase);
    const int4 i0 = ip[0];
    const int4 i1 = ip[1];
    int rows[RPW];
    rows[0] = i0.x; rows[1] = i0.y; rows[2] = i0.z; rows[3] = i0.w;
    rows[4] = i1.x; rows[5] = i1.y; rows[6] = i1.z; rows[7] = i1.w;

    v4f v[RPW];
    #pragma unroll
    for (int r = 0; r < RPW; ++r) {
        const v4f* rowp =
            reinterpret_cast<const v4f*>(emb + (long long)rows[r] * EMBED);
        v[r] = rowp[lane];
    }

    float s[RPW];
    #pragma unroll
    for (int r = 0; r < RPW; ++r) {
        const float ex = __expf(v[r].x);
        const float ey = __expf(v[r].y);
        const float ez = __expf(v[r].z);
        const float ew = __expf(v[r].w);
        s[r] = (ex + ey) + (ez + ew);
    }

    #pragma unroll
    for (int m = 1; m < 64; m <<= 1) {
        #pragma unroll
        for (int r = 0; r < RPW; ++r)
            s[r] += __shfl_xor(s[r], m, 64);
    }

    v4f* lp = reinterpret_cast<v4f*>(logits);
    v4f* pp = reinterpret_cast<v4f*>(probs);
    #pragma unroll
    for (int r = 0; r < RPW; ++r) {
        const float inv = 1.0f / s[r];
        v4f p;
        p.x = __expf(v[r].x) * inv;
        p.y = __expf(v[r].y) * inv;
        p.z = __expf(v[r].z) * inv;
        p.w = __expf(v[r].w) * inv;

        const long long off = (rowbase + r) * (EMBED / 4) + lane;
        __builtin_nontemporal_store(v[r], lp + off);
        __builtin_nontemporal_store(p,    pp + off);
    }
}

extern "C" void kernel_launch(void* const* d_in, const int* in_sizes, int n_in,
                              void* d_out, int out_size, void* d_ws, size_t ws_size,
                              hipStream_t stream) {
    const int*   idx = (const int*)d_in[0];
    const float* emb = (const float*)d_in[1];

    float* out    = (float*)d_out;
    float* logits = out;                              // [ROWS, EMBED]
    float* probs  = out + (long long)ROWS * EMBED;    // [ROWS, EMBED]

    const int blocks = ROWS / ROWS_PER_BLOCK;         // 4096

    // Phase 1: pure-read warm of the Infinity Cache (no write mixing).
    warm_kernel<<<blocks, 256, 0, stream>>>(idx, emb);
    // Phase 2: compute + stream outputs (gathers hit L3).
    embed_expnorm_kernel<<<blocks, 256, 0, stream>>>(idx, emb, logits, probs);
}